// Round 4
// baseline (234.464 us; speedup 1.0000x reference)
//
#include <hip/hip_runtime.h>

#define SGRID 28
#define NBATCH 1024
constexpr int CELLS = NBATCH * SGRID * SGRID;   // 802816
constexpr int TPB   = 256;
constexpr int CPT   = 2;                        // cells per thread (2*30 floats = 15 aligned float4)
constexpr int NBLK  = CELLS / (TPB * CPT);      // 1568
constexpr float L_COORD = 5.0f;
constexpr float L_NOOBJ = 0.5f;

// No LDS staging, no barriers in the hot path: each thread owns 2 cells
// (240 B of pred = 15 float4, 160 B of tcls = 10 float4, all 16-B aligned).
// Loads go straight to VGPRs; waves free-run -> continuous global-load issue.
__global__ __launch_bounds__(256, 4) void yolo_main(
    const float* __restrict__ pred,      // CELLS*30
    const float* __restrict__ tboxes,    // CELLS*4
    const float* __restrict__ tcls,      // CELLS*20
    const int*   __restrict__ objmap,    // CELLS
    float4* __restrict__ partials)       // NBLK partial sums: {reg, cobj, nbj, cls}
{
    const int tid = threadIdx.x;
    const int gid = blockIdx.x * TPB + tid;      // [0, 401408)

    const float4* pp  = reinterpret_cast<const float4*>(pred)   + (size_t)gid * 15;
    const float4* tc  = reinterpret_cast<const float4*>(tcls)   + (size_t)gid * 10;
    const float4* tbx = reinterpret_cast<const float4*>(tboxes) + (size_t)gid * 2;

    // ---- direct register loads ----
    float4 p4[15];
    #pragma unroll
    for (int i = 0; i < 15; ++i) p4[i] = pp[i];
    const float4 tbA = tbx[0];
    const float4 tbB = tbx[1];
    const int2   om  = reinterpret_cast<const int2*>(objmap)[gid];

    float pr[60];
    #pragma unroll
    for (int i = 0; i < 15; ++i) {
        pr[4*i+0] = p4[i].x; pr[4*i+1] = p4[i].y;
        pr[4*i+2] = p4[i].z; pr[4*i+3] = p4[i].w;
    }

    const float fm_[2]  = { om.x ? 1.f : 0.f, om.y ? 1.f : 0.f };
    const float4 tb_[2] = { tbA, tbB };

    float reg = 0.f, cobj = 0.f, nbj = 0.f, clsv = 0.f;
    const float invS = 1.0f / SGRID;

    #pragma unroll
    for (int c = 0; c < 2; ++c) {
        const int   qb  = c * 30;                // compile-time after unroll
        const float fm  = fm_[c];
        const float4 tbv = tb_[c];

        float tx = tbv.x * invS, ty = tbv.y * invS;
        float thw = 0.5f * tbv.z, thh = 0.5f * tbv.w;
        float tx1 = tx - thw, ty1 = ty - thh, tx2 = tx + thw, ty2 = ty + thh;
        float ta = (tx2 - tx1) * (ty2 - ty1);

        float bx1[2], by1[2], bx2[2], by2[2], bcf[2], biou[2];
        #pragma unroll
        for (int b = 0; b < 2; ++b) {
            float cx = pr[qb + b*5 + 0] * invS, cy = pr[qb + b*5 + 1] * invS;
            float hw = 0.5f * pr[qb + b*5 + 2], hh = 0.5f * pr[qb + b*5 + 3];
            float x1 = cx - hw, y1 = cy - hh, x2 = cx + hw, y2 = cy + hh;
            bx1[b] = x1; by1[b] = y1; bx2[b] = x2; by2[b] = y2;
            bcf[b] = pr[qb + b*5 + 4];
            float ltx = fmaxf(x1, tx1), lty = fmaxf(y1, ty1);
            float rbx = fminf(x2, tx2), rby = fminf(y2, ty2);
            float wi = fmaxf(rbx - ltx, 0.f), hi = fmaxf(rby - lty, 0.f);
            float inter = wi * hi;
            float a1 = (x2 - x1) * (y2 - y1);
            biou[b] = inter / (a1 + ta - inter);
        }
        int sel = (biou[1] > biou[0]) ? 1 : 0;   // strict '>' == first-max tie-break
        float best_iou = biou[sel];
        bool valid = best_iou > 0.f;
        float bbx1 = valid ? bx1[sel] : 0.f;
        float bby1 = valid ? by1[sel] : 0.f;
        float bbx2 = valid ? bx2[sel] : 0.f;
        float bby2 = valid ? by2[sel] : 0.f;
        float bcfs = valid ? bcf[sel] : 0.f;
        best_iou   = valid ? best_iou : 0.f;

        float dx = bbx1 - tx1, dy = bby1 - ty1;
        float lxy = dx * dx + dy * dy;
        auto ssqrt = [](float x) { return x > 0.f ? sqrtf(x) : 0.f; };
        float dwx = ssqrt(bbx2) - ssqrt(tx2);
        float dwy = ssqrt(bby2) - ssqrt(ty2);
        float lwh = dwx * dwx + dwy * dwy;
        reg += fm * (lxy + lwh);

        float c0 = pr[qb + 4], c1 = pr[qb + 9];
        nbj += (1.f - fm) * (c0 * c0 + c1 * c1);

        float dc = bcfs - best_iou;
        cobj += fm * dc * dc;

        // ---- cls loss for this cell (tcls float4s c*5 .. c*5+4) ----
        #pragma unroll
        for (int i = 0; i < 5; ++i) {
            float4 t4 = tc[c*5 + i];
            float d0 = pr[qb + 10 + 4*i + 0] - t4.x;
            float d1 = pr[qb + 10 + 4*i + 1] - t4.y;
            float d2 = pr[qb + 10 + 4*i + 2] - t4.z;
            float d3 = pr[qb + 10 + 4*i + 3] - t4.w;
            clsv += fm * (d0 * d0 + d1 * d1 + d2 * d2 + d3 * d3);
        }
    }

    // ---- reduction: wave64 shuffle, then cross-wave via LDS (only sync point) ----
    #pragma unroll
    for (int off = 32; off > 0; off >>= 1) {
        reg  += __shfl_down(reg,  off);
        cobj += __shfl_down(cobj, off);
        nbj  += __shfl_down(nbj,  off);
        clsv += __shfl_down(clsv, off);
    }
    __shared__ float sred[4][4];
    int wave = tid >> 6, lane = tid & 63;
    if (lane == 0) {
        sred[wave][0] = reg; sred[wave][1] = cobj;
        sred[wave][2] = nbj; sred[wave][3] = clsv;
    }
    __syncthreads();
    if (tid == 0) {
        float4 s;
        s.x = sred[0][0] + sred[1][0] + sred[2][0] + sred[3][0];
        s.y = sred[0][1] + sred[1][1] + sred[2][1] + sred[3][1];
        s.z = sred[0][2] + sred[1][2] + sred[2][2] + sred[3][2];
        s.w = sred[0][3] + sred[1][3] + sred[2][3] + sred[3][3];
        partials[blockIdx.x] = s;
    }
}

__global__ __launch_bounds__(256) void yolo_finalize(
    const float4* __restrict__ partials, float* __restrict__ out)
{
    float4 s = {0.f, 0.f, 0.f, 0.f};
    for (int b = threadIdx.x; b < NBLK; b += 256) {
        float4 v = partials[b];
        s.x += v.x; s.y += v.y; s.z += v.z; s.w += v.w;
    }
    #pragma unroll
    for (int off = 32; off > 0; off >>= 1) {
        s.x += __shfl_down(s.x, off);
        s.y += __shfl_down(s.y, off);
        s.z += __shfl_down(s.z, off);
        s.w += __shfl_down(s.w, off);
    }
    __shared__ float4 sw[4];
    int wave = threadIdx.x >> 6, lane = threadIdx.x & 63;
    if (lane == 0) sw[wave] = s;
    __syncthreads();
    if (threadIdx.x == 0) {
        float r = 0.f, c = 0.f, n = 0.f, cl = 0.f;
        #pragma unroll
        for (int w = 0; w < 4; ++w) {
            r += sw[w].x; c += sw[w].y; n += sw[w].z; cl += sw[w].w;
        }
        const float invN = 1.0f / NBATCH;
        float reg_l  = L_COORD * r * invN;
        float cobj_l = c * invN;
        float nbj_l  = L_NOOBJ * n * invN;
        float cls_l  = 2.0f * cl * invN;
        out[0] = cls_l + nbj_l + reg_l + cobj_l;
        out[1] = reg_l;
        out[2] = cobj_l;
        out[3] = nbj_l;
        out[4] = cls_l;
    }
}

extern "C" void kernel_launch(void* const* d_in, const int* in_sizes, int n_in,
                              void* d_out, int out_size, void* d_ws, size_t ws_size,
                              hipStream_t stream) {
    const float* pred   = (const float*)d_in[0];
    const float* tboxes = (const float*)d_in[1];
    const float* tcls   = (const float*)d_in[2];
    const int*   objmap = (const int*)d_in[3];
    float4* partials = (float4*)d_ws;
    float*  out      = (float*)d_out;

    yolo_main<<<NBLK, 256, 0, stream>>>(pred, tboxes, tcls, objmap, partials);
    yolo_finalize<<<1, 256, 0, stream>>>(partials, out);
}

// Round 5
// 228.403 us; speedup vs baseline: 1.0265x; 1.0265x over previous
//
#include <hip/hip_runtime.h>

#define SGRID 28
#define NBATCH 1024
constexpr int CELLS = NBATCH * SGRID * SGRID;   // 802816
constexpr int TPB   = 256;
constexpr int SLAB  = 256;                      // cells per slab (thread t <-> cell t)
constexpr int NS    = 4;                        // slabs per block
constexpr int NBLK  = CELLS / (SLAB * NS);      // 784
constexpr float L_COORD = 5.0f;
constexpr float L_NOOBJ = 0.5f;

// Raw barrier WITHOUT vmcnt drain: ds ops must be visible (lgkmcnt(0)) but
// prefetch global loads stay in flight across the barrier (T3/T4 idiom).
#define PIPE_BARRIER() do { \
    asm volatile("s_waitcnt lgkmcnt(0)" ::: "memory"); \
    __builtin_amdgcn_s_barrier(); \
} while (0)

__global__ __launch_bounds__(256, 2) void yolo_main(
    const float* __restrict__ pred,      // CELLS*30
    const float* __restrict__ tboxes,    // CELLS*4
    const float* __restrict__ tcls,      // CELLS*20
    const int*   __restrict__ objmap,    // CELLS
    float4* __restrict__ partials)       // NBLK partials {reg, cobj, nbj, cls}
{
    __shared__ float spred[2][SLAB * 30];   // 2 x 30720 B, double-buffered pred slab
    __shared__ float smask[2][SLAB];        // 2 x 1024 B
    __shared__ float sred[4][4];

    const int tid   = threadIdx.x;
    const int slab0 = blockIdx.x * NS;

    const float4* pred4 = reinterpret_cast<const float4*>(pred);
    const float4* tb4   = reinterpret_cast<const float4*>(tboxes);
    const float4* tc4   = reinterpret_cast<const float4*>(tcls);

    // Two static register sets (A/B) -> all indexing compile-time (no scratch).
    float4 pfA[8], pfB[8];          // pred slab staging (unit-stride float4)
    float4 tbA, tbB;                // own-cell target box
    int    omA, omB;                // own-cell object flag
    float4 tcA[5], tcB[5];          // tcls flat slab slice (unit-stride float4)

    float reg = 0.f, cobj = 0.f, nbj = 0.f, clsv = 0.f;
    const float invS = 1.0f / SGRID;

    auto LOADA = [&](int s) {
        const float4* pb = pred4 + (size_t)(slab0 + s) * 1920;   // 256*30/4
        #pragma unroll
        for (int i = 0; i < 7; ++i) pfA[i] = pb[tid + i * 256];
        if (tid < 128) pfA[7] = pb[tid + 1792];
        const int cb = (slab0 + s) * SLAB;
        tbA = tb4[cb + tid];
        omA = objmap[cb + tid];
        const float4* tcb = tc4 + (size_t)cb * 5;
        #pragma unroll
        for (int i = 0; i < 5; ++i) tcA[i] = tcb[tid + i * 256];
    };
    auto LOADB = [&](int s) {
        const float4* pb = pred4 + (size_t)(slab0 + s) * 1920;
        #pragma unroll
        for (int i = 0; i < 7; ++i) pfB[i] = pb[tid + i * 256];
        if (tid < 128) pfB[7] = pb[tid + 1792];
        const int cb = (slab0 + s) * SLAB;
        tbB = tb4[cb + tid];
        omB = objmap[cb + tid];
        const float4* tcb = tc4 + (size_t)cb * 5;
        #pragma unroll
        for (int i = 0; i < 5; ++i) tcB[i] = tcb[tid + i * 256];
    };
    auto WRITEA = [&](int buf) {
        float4* sp4 = reinterpret_cast<float4*>(spred[buf]);
        #pragma unroll
        for (int i = 0; i < 7; ++i) sp4[tid + i * 256] = pfA[i];
        if (tid < 128) sp4[tid + 1792] = pfA[7];
        smask[buf][tid] = omA ? 1.f : 0.f;
    };
    auto WRITEB = [&](int buf) {
        float4* sp4 = reinterpret_cast<float4*>(spred[buf]);
        #pragma unroll
        for (int i = 0; i < 7; ++i) sp4[tid + i * 256] = pfB[i];
        if (tid < 128) sp4[tid + 1792] = pfB[7];
        smask[buf][tid] = omB ? 1.f : 0.f;
    };

    auto COMPUTE = [&](int buf, const float4& tbv, int om, const float4 (&tcv)[5]) {
        // ---- box math: thread t = cell t (LDS stride 30 floats) ----
        const float* q = &spred[buf][tid * 30];
        const float fm = om ? 1.f : 0.f;

        float tx = tbv.x * invS, ty = tbv.y * invS;
        float thw = 0.5f * tbv.z, thh = 0.5f * tbv.w;
        float tx1 = tx - thw, ty1 = ty - thh, tx2 = tx + thw, ty2 = ty + thh;
        float ta = (tx2 - tx1) * (ty2 - ty1);

        float bx1[2], by1[2], bx2[2], by2[2], bcf[2], biou[2];
        #pragma unroll
        for (int b = 0; b < 2; ++b) {
            float cx = q[b*5+0] * invS, cy = q[b*5+1] * invS;
            float hw = 0.5f * q[b*5+2], hh = 0.5f * q[b*5+3];
            float x1 = cx - hw, y1 = cy - hh, x2 = cx + hw, y2 = cy + hh;
            bx1[b] = x1; by1[b] = y1; bx2[b] = x2; by2[b] = y2; bcf[b] = q[b*5+4];
            float ltx = fmaxf(x1, tx1), lty = fmaxf(y1, ty1);
            float rbx = fminf(x2, tx2), rby = fminf(y2, ty2);
            float wi = fmaxf(rbx - ltx, 0.f), hi = fmaxf(rby - lty, 0.f);
            float inter = wi * hi;
            float a1 = (x2 - x1) * (y2 - y1);
            biou[b] = inter / (a1 + ta - inter);
        }
        int sel = (biou[1] > biou[0]) ? 1 : 0;   // strict '>' == first-max tie-break
        float best_iou = biou[sel];
        bool valid = best_iou > 0.f;
        float bbx1 = valid ? bx1[sel] : 0.f;
        float bby1 = valid ? by1[sel] : 0.f;
        float bbx2 = valid ? bx2[sel] : 0.f;
        float bby2 = valid ? by2[sel] : 0.f;
        float bcfs = valid ? bcf[sel] : 0.f;
        best_iou   = valid ? best_iou : 0.f;

        float dx = bbx1 - tx1, dy = bby1 - ty1;
        float lxy = dx * dx + dy * dy;
        auto ssqrt = [](float x) { return x > 0.f ? sqrtf(x) : 0.f; };
        float dwx = ssqrt(bbx2) - ssqrt(tx2);
        float dwy = ssqrt(bby2) - ssqrt(ty2);
        float lwh = dwx * dwx + dwy * dwy;
        reg += fm * (lxy + lwh);

        float c0 = q[4], c1 = q[9];
        nbj += (1.f - fm) * (c0 * c0 + c1 * c1);

        float dc = bcfs - best_iou;
        cobj += fm * dc * dc;

        // ---- cls loss: flat unit-stride tcls (regs), pred from LDS ----
        #pragma unroll
        for (int i = 0; i < 5; ++i) {
            int e = tid + i * 256;              // [0, 1280)
            int cell = e / 5;
            int c0i  = (e - cell * 5) * 4;
            const float* pc = &spred[buf][cell * 30 + 10 + c0i];
            float mk = smask[buf][cell];
            float4 tv = tcv[i];
            float d0 = pc[0] - tv.x, d1 = pc[1] - tv.y;
            float d2 = pc[2] - tv.z, d3 = pc[3] - tv.w;
            clsv += mk * (d0 * d0 + d1 * d1 + d2 * d2 + d3 * d3);
        }
    };

    // ---- software pipeline over NS=4 slabs, one-slab-ahead prefetch ----
    LOADA(0);
    WRITEA(0);                 // compiler waits A-loads (vmcnt), ds_writes buf0
    LOADB(1);                  // in flight across the barrier
    PIPE_BARRIER();

    COMPUTE(0, tbA, omA, tcA); // slab 0
    LOADA(2);                  // issue next-next before waiting on B
    WRITEB(1);                 // partial vmcnt wait for B only
    PIPE_BARRIER();

    COMPUTE(1, tbB, omB, tcB); // slab 1
    LOADB(3);
    WRITEA(0);
    PIPE_BARRIER();

    COMPUTE(0, tbA, omA, tcA); // slab 2
    WRITEB(1);
    PIPE_BARRIER();

    COMPUTE(1, tbB, omB, tcB); // slab 3

    // ---- reduction: wave64 shuffle, then cross-wave via LDS ----
    #pragma unroll
    for (int off = 32; off > 0; off >>= 1) {
        reg  += __shfl_down(reg,  off);
        cobj += __shfl_down(cobj, off);
        nbj  += __shfl_down(nbj,  off);
        clsv += __shfl_down(clsv, off);
    }
    int wave = tid >> 6, lane = tid & 63;
    if (lane == 0) {
        sred[wave][0] = reg; sred[wave][1] = cobj;
        sred[wave][2] = nbj; sred[wave][3] = clsv;
    }
    __syncthreads();
    if (tid == 0) {
        float4 s;
        s.x = sred[0][0] + sred[1][0] + sred[2][0] + sred[3][0];
        s.y = sred[0][1] + sred[1][1] + sred[2][1] + sred[3][1];
        s.z = sred[0][2] + sred[1][2] + sred[2][2] + sred[3][2];
        s.w = sred[0][3] + sred[1][3] + sred[2][3] + sred[3][3];
        partials[blockIdx.x] = s;
    }
}

__global__ __launch_bounds__(256) void yolo_finalize(
    const float4* __restrict__ partials, float* __restrict__ out)
{
    float4 s = {0.f, 0.f, 0.f, 0.f};
    for (int b = threadIdx.x; b < NBLK; b += 256) {
        float4 v = partials[b];
        s.x += v.x; s.y += v.y; s.z += v.z; s.w += v.w;
    }
    #pragma unroll
    for (int off = 32; off > 0; off >>= 1) {
        s.x += __shfl_down(s.x, off);
        s.y += __shfl_down(s.y, off);
        s.z += __shfl_down(s.z, off);
        s.w += __shfl_down(s.w, off);
    }
    __shared__ float4 sw[4];
    int wave = threadIdx.x >> 6, lane = threadIdx.x & 63;
    if (lane == 0) sw[wave] = s;
    __syncthreads();
    if (threadIdx.x == 0) {
        float r = 0.f, c = 0.f, n = 0.f, cl = 0.f;
        #pragma unroll
        for (int w = 0; w < 4; ++w) {
            r += sw[w].x; c += sw[w].y; n += sw[w].z; cl += sw[w].w;
        }
        const float invN = 1.0f / NBATCH;
        float reg_l  = L_COORD * r * invN;
        float cobj_l = c * invN;
        float nbj_l  = L_NOOBJ * n * invN;
        float cls_l  = 2.0f * cl * invN;
        out[0] = cls_l + nbj_l + reg_l + cobj_l;
        out[1] = reg_l;
        out[2] = cobj_l;
        out[3] = nbj_l;
        out[4] = cls_l;
    }
}

extern "C" void kernel_launch(void* const* d_in, const int* in_sizes, int n_in,
                              void* d_out, int out_size, void* d_ws, size_t ws_size,
                              hipStream_t stream) {
    const float* pred   = (const float*)d_in[0];
    const float* tboxes = (const float*)d_in[1];
    const float* tcls   = (const float*)d_in[2];
    const int*   objmap = (const int*)d_in[3];
    float4* partials = (float4*)d_ws;
    float*  out      = (float*)d_out;

    yolo_main<<<NBLK, 256, 0, stream>>>(pred, tboxes, tcls, objmap, partials);
    yolo_finalize<<<1, 256, 0, stream>>>(partials, out);
}

// Round 6
// 210.620 us; speedup vs baseline: 1.1132x; 1.0844x over previous
//
#include <hip/hip_runtime.h>

#define SGRID 28
#define NBATCH 1024
constexpr int CELLS = NBATCH * SGRID * SGRID;   // 802816
constexpr int TPB   = 256;
constexpr int WSLAB = 64;                       // cells per wave-slab (1 cell per lane)
constexpr int NS    = 4;                        // slabs per wave
constexpr int CPB   = 4 * WSLAB * NS;           // cells per block = 1024
constexpr int NBLK  = CELLS / CPB;              // 784
constexpr float L_COORD = 5.0f;
constexpr float L_NOOBJ = 0.5f;

// Wave-private slabs: LDS traffic is same-wave only (in-order DS pipe), so the
// hot path has ZERO __syncthreads -> no vmcnt(0) drain ever gates the loads.
// Staging: 15 unit-stride float2 per lane (exactly uniform), double-buffered
// in registers (30 VGPR/buf). Mask for the cls loop comes from __shfl.

#define LOADP(P, tbv, om, s) do {                                        \
    const int cb_ = wbase + (s) * WSLAB;                                 \
    const float2* pp_ = pred2 + (size_t)cb_ * 15;                        \
    _Pragma("unroll")                                                    \
    for (int i_ = 0; i_ < 15; ++i_) P[i_] = pp_[lane + 64 * i_];         \
    tbv = tb4[cb_ + lane];                                               \
    om  = objmap[cb_ + lane];                                            \
} while (0)

#define DSWRITE(P) do {                                                  \
    _Pragma("unroll")                                                    \
    for (int i_ = 0; i_ < 15; ++i_) sp2[lane + 64 * i_] = P[i_];         \
} while (0)

#define COMPUTE(tbv, om, s) do {                                         \
    const int cb_ = wbase + (s) * WSLAB;                                 \
    /* tcls: issued first, consumed at the end of this phase */          \
    float4 tcv[5];                                                       \
    const float4* tcb_ = tc4 + (size_t)cb_ * 5;                          \
    _Pragma("unroll")                                                    \
    for (int i_ = 0; i_ < 5; ++i_) tcv[i_] = tcb_[lane + 64 * i_];       \
    const float fm = (om) ? 1.f : 0.f;                                   \
    const float* q = swave + lane * 30;                                  \
    float tx = tbv.x * invS, ty = tbv.y * invS;                          \
    float thw = 0.5f * tbv.z, thh = 0.5f * tbv.w;                        \
    float tx1 = tx - thw, ty1 = ty - thh, tx2 = tx + thw, ty2 = ty + thh;\
    float ta = (tx2 - tx1) * (ty2 - ty1);                                \
    float bx1[2], by1[2], bx2[2], by2[2], bcf[2], biou[2];               \
    _Pragma("unroll")                                                    \
    for (int b = 0; b < 2; ++b) {                                        \
        float cx = q[b*5+0] * invS, cy = q[b*5+1] * invS;                \
        float hw = 0.5f * q[b*5+2], hh = 0.5f * q[b*5+3];                \
        float x1 = cx - hw, y1 = cy - hh, x2 = cx + hw, y2 = cy + hh;    \
        bx1[b] = x1; by1[b] = y1; bx2[b] = x2; by2[b] = y2;              \
        bcf[b] = q[b*5+4];                                               \
        float ltx = fmaxf(x1, tx1), lty = fmaxf(y1, ty1);                \
        float rbx = fminf(x2, tx2), rby = fminf(y2, ty2);                \
        float wi = fmaxf(rbx - ltx, 0.f), hi = fmaxf(rby - lty, 0.f);    \
        float inter = wi * hi;                                           \
        float a1 = (x2 - x1) * (y2 - y1);                                \
        biou[b] = inter / (a1 + ta - inter);                             \
    }                                                                    \
    int sel = (biou[1] > biou[0]) ? 1 : 0;                               \
    float best_iou = biou[sel];                                          \
    bool valid = best_iou > 0.f;                                         \
    float bbx1 = valid ? bx1[sel] : 0.f;                                 \
    float bby1 = valid ? by1[sel] : 0.f;                                 \
    float bbx2 = valid ? bx2[sel] : 0.f;                                 \
    float bby2 = valid ? by2[sel] : 0.f;                                 \
    float bcfs = valid ? bcf[sel] : 0.f;                                 \
    best_iou   = valid ? best_iou : 0.f;                                 \
    float dx = bbx1 - tx1, dy = bby1 - ty1;                              \
    float lxy = dx * dx + dy * dy;                                       \
    float swx = bbx2 > 0.f ? sqrtf(bbx2) : 0.f;                          \
    float swy = bby2 > 0.f ? sqrtf(bby2) : 0.f;                          \
    float twx = tx2 > 0.f ? sqrtf(tx2) : 0.f;                            \
    float twy = ty2 > 0.f ? sqrtf(ty2) : 0.f;                            \
    float dwx = swx - twx, dwy = swy - twy;                              \
    reg += fm * (lxy + dwx * dwx + dwy * dwy);                           \
    float c0 = q[4], c1 = q[9];                                          \
    nbj += (1.f - fm) * (c0 * c0 + c1 * c1);                             \
    float dcf = bcfs - best_iou;                                         \
    cobj += fm * dcf * dcf;                                              \
    _Pragma("unroll")                                                    \
    for (int i_ = 0; i_ < 5; ++i_) {                                     \
        int e = lane + 64 * i_;                                          \
        int cell = e / 5;                                                \
        int c0i  = (e - cell * 5) * 4;                                   \
        const float* pc = swave + cell * 30 + 10 + c0i;                  \
        float mk = __shfl(fm, cell, 64);                                 \
        float4 tv = tcv[i_];                                             \
        float d0 = pc[0] - tv.x, d1 = pc[1] - tv.y;                      \
        float d2 = pc[2] - tv.z, d3 = pc[3] - tv.w;                      \
        clsv += mk * (d0 * d0 + d1 * d1 + d2 * d2 + d3 * d3);            \
    }                                                                    \
} while (0)

__global__ __launch_bounds__(256, 3) void yolo_main(
    const float* __restrict__ pred,      // CELLS*30
    const float* __restrict__ tboxes,    // CELLS*4
    const float* __restrict__ tcls,      // CELLS*20
    const int*   __restrict__ objmap,    // CELLS
    float4* __restrict__ partials)       // NBLK partials {reg, cobj, nbj, cls}
{
    __shared__ float spred[4][WSLAB * 30];   // 4 waves x 7680 B, wave-private
    __shared__ float sred[4][4];

    const int tid  = threadIdx.x;
    const int lane = tid & 63;
    const int wid  = tid >> 6;
    const int wbase = blockIdx.x * CPB + wid * (WSLAB * NS);

    const float2* pred2 = reinterpret_cast<const float2*>(pred);
    const float4* tb4   = reinterpret_cast<const float4*>(tboxes);
    const float4* tc4   = reinterpret_cast<const float4*>(tcls);

    float*  swave = &spred[wid][0];
    float2* sp2   = reinterpret_cast<float2*>(swave);

    float reg = 0.f, cobj = 0.f, nbj = 0.f, clsv = 0.f;
    const float invS = 1.0f / SGRID;

    float2 PA[15], PB[15];
    float4 tb0, tb1, tb2, tb3;
    int    om0, om1, om2, om3;

    // ---- software pipeline, fully unrolled, no barriers ----
    LOADP(PA, tb0, om0, 0);
    LOADP(PB, tb1, om1, 1);      // both slabs' loads in flight

    DSWRITE(PA);                 // slab 0 -> LDS (vmcnt for PA auto-counted)
    LOADP(PA, tb2, om2, 2);      // reuse PA regs immediately after ds_write issue
    COMPUTE(tb0, om0, 0);        // reads slab 0 (lgkmcnt auto)

    DSWRITE(PB);                 // slab 1 (PB landed during compute 0)
    LOADP(PB, tb3, om3, 3);
    COMPUTE(tb1, om1, 1);

    DSWRITE(PA);                 // slab 2
    COMPUTE(tb2, om2, 2);

    DSWRITE(PB);                 // slab 3
    COMPUTE(tb3, om3, 3);

    // ---- reduction: wave64 shuffle, then cross-wave via LDS ----
    #pragma unroll
    for (int off = 32; off > 0; off >>= 1) {
        reg  += __shfl_down(reg,  off);
        cobj += __shfl_down(cobj, off);
        nbj  += __shfl_down(nbj,  off);
        clsv += __shfl_down(clsv, off);
    }
    if (lane == 0) {
        sred[wid][0] = reg; sred[wid][1] = cobj;
        sred[wid][2] = nbj; sred[wid][3] = clsv;
    }
    __syncthreads();
    if (tid == 0) {
        float4 s;
        s.x = sred[0][0] + sred[1][0] + sred[2][0] + sred[3][0];
        s.y = sred[0][1] + sred[1][1] + sred[2][1] + sred[3][1];
        s.z = sred[0][2] + sred[1][2] + sred[2][2] + sred[3][2];
        s.w = sred[0][3] + sred[1][3] + sred[2][3] + sred[3][3];
        partials[blockIdx.x] = s;
    }
}

__global__ __launch_bounds__(256) void yolo_finalize(
    const float4* __restrict__ partials, float* __restrict__ out)
{
    float4 s = {0.f, 0.f, 0.f, 0.f};
    for (int b = threadIdx.x; b < NBLK; b += 256) {
        float4 v = partials[b];
        s.x += v.x; s.y += v.y; s.z += v.z; s.w += v.w;
    }
    #pragma unroll
    for (int off = 32; off > 0; off >>= 1) {
        s.x += __shfl_down(s.x, off);
        s.y += __shfl_down(s.y, off);
        s.z += __shfl_down(s.z, off);
        s.w += __shfl_down(s.w, off);
    }
    __shared__ float4 sw[4];
    int wave = threadIdx.x >> 6, lane = threadIdx.x & 63;
    if (lane == 0) sw[wave] = s;
    __syncthreads();
    if (threadIdx.x == 0) {
        float r = 0.f, c = 0.f, n = 0.f, cl = 0.f;
        #pragma unroll
        for (int w = 0; w < 4; ++w) {
            r += sw[w].x; c += sw[w].y; n += sw[w].z; cl += sw[w].w;
        }
        const float invN = 1.0f / NBATCH;
        float reg_l  = L_COORD * r * invN;
        float cobj_l = c * invN;
        float nbj_l  = L_NOOBJ * n * invN;
        float cls_l  = 2.0f * cl * invN;
        out[0] = cls_l + nbj_l + reg_l + cobj_l;
        out[1] = reg_l;
        out[2] = cobj_l;
        out[3] = nbj_l;
        out[4] = cls_l;
    }
}

extern "C" void kernel_launch(void* const* d_in, const int* in_sizes, int n_in,
                              void* d_out, int out_size, void* d_ws, size_t ws_size,
                              hipStream_t stream) {
    const float* pred   = (const float*)d_in[0];
    const float* tboxes = (const float*)d_in[1];
    const float* tcls   = (const float*)d_in[2];
    const int*   objmap = (const int*)d_in[3];
    float4* partials = (float4*)d_ws;
    float*  out      = (float*)d_out;

    yolo_main<<<NBLK, 256, 0, stream>>>(pred, tboxes, tcls, objmap, partials);
    yolo_finalize<<<1, 256, 0, stream>>>(partials, out);
}

// Round 9
// 203.163 us; speedup vs baseline: 1.1541x; 1.0367x over previous
//
#include <hip/hip_runtime.h>

#define SGRID 28
#define NBATCH 1024
constexpr int CELLS = NBATCH * SGRID * SGRID;   // 802816
constexpr int TPB   = 256;
constexpr int WSLAB = 64;                       // cells per wave-slab (1 cell per lane)
constexpr int CPB   = 4 * WSLAB;                // cells per block = 256
constexpr int NBLK  = CELLS / CPB;              // 3136  (12.25 blocks/CU queued)
constexpr float L_COORD = 5.0f;
constexpr float L_NOOBJ = 0.5f;

// Wave-private slab, zero barriers in the hot path (verified R6): LDS traffic
// is same-wave only, so staging-write -> compute-read needs only the
// compiler's counted lgkmcnt. Per-wave vmcnt waits don't gate other waves.
// NS=1 (vs R6's NS=4) restores baseline's grid: 3136 blocks, 5 resident
// blocks/CU (LDS-limited) = 20 waves/CU + refill queue -> TLP hides latency.
__global__ __launch_bounds__(256) void yolo_main(
    const float* __restrict__ pred,      // CELLS*30
    const float* __restrict__ tboxes,    // CELLS*4
    const float* __restrict__ tcls,      // CELLS*20
    const int*   __restrict__ objmap,    // CELLS
    float4* __restrict__ partials)       // NBLK partials {reg, cobj, nbj, cls}
{
    __shared__ float spred[4][WSLAB * 30];   // 4 waves x 7680 B, wave-private
    __shared__ float sred[4][4];

    const int tid   = threadIdx.x;
    const int lane  = tid & 63;
    const int wid   = tid >> 6;
    const int wbase = blockIdx.x * CPB + wid * WSLAB;

    const float2* pred2 = reinterpret_cast<const float2*>(pred);
    const float4* tb4   = reinterpret_cast<const float4*>(tboxes);
    const float4* tc4   = reinterpret_cast<const float4*>(tcls);

    float*  swave = &spred[wid][0];
    float2* sp2   = reinterpret_cast<float2*>(swave);

    const float invS = 1.0f / SGRID;

    // ---- issue all global loads up front (compiler emits counted vmcnt) ----
    float2 P[15];                                 // pred slab, unit-stride float2
    const float2* pp = pred2 + (size_t)wbase * 15;
    #pragma unroll
    for (int i = 0; i < 15; ++i) P[i] = pp[lane + 64 * i];

    const float4 tbv = tb4[wbase + lane];
    const int    om  = objmap[wbase + lane];

    float4 tcv[5];                                // tcls window, unit-stride float4
    const float4* tcb = tc4 + (size_t)wbase * 5;
    #pragma unroll
    for (int i = 0; i < 5; ++i) tcv[i] = tcb[lane + 64 * i];

    // ---- stage pred slab into wave-private LDS (transpose to per-cell) ----
    #pragma unroll
    for (int i = 0; i < 15; ++i) sp2[lane + 64 * i] = P[i];

    // ---- per-cell box math (lane = cell, LDS stride 30 floats) ----
    const float fm = om ? 1.f : 0.f;
    const float* q = swave + lane * 30;

    float reg, cobj, nbj, clsv = 0.f;
    {
        float tx = tbv.x * invS, ty = tbv.y * invS;
        float thw = 0.5f * tbv.z, thh = 0.5f * tbv.w;
        float tx1 = tx - thw, ty1 = ty - thh, tx2 = tx + thw, ty2 = ty + thh;
        float ta = (tx2 - tx1) * (ty2 - ty1);

        float bx1[2], by1[2], bx2[2], by2[2], bcf[2], biou[2];
        #pragma unroll
        for (int b = 0; b < 2; ++b) {
            float cx = q[b*5+0] * invS, cy = q[b*5+1] * invS;
            float hw = 0.5f * q[b*5+2], hh = 0.5f * q[b*5+3];
            float x1 = cx - hw, y1 = cy - hh, x2 = cx + hw, y2 = cy + hh;
            bx1[b] = x1; by1[b] = y1; bx2[b] = x2; by2[b] = y2;
            bcf[b] = q[b*5+4];
            float ltx = fmaxf(x1, tx1), lty = fmaxf(y1, ty1);
            float rbx = fminf(x2, tx2), rby = fminf(y2, ty2);
            float wi = fmaxf(rbx - ltx, 0.f), hi = fmaxf(rby - lty, 0.f);
            float inter = wi * hi;
            float a1 = (x2 - x1) * (y2 - y1);
            biou[b] = inter / (a1 + ta - inter);
        }
        int sel = (biou[1] > biou[0]) ? 1 : 0;   // strict '>' == first-max tie-break
        float best_iou = biou[sel];
        bool valid = best_iou > 0.f;
        float bbx1 = valid ? bx1[sel] : 0.f;
        float bby1 = valid ? by1[sel] : 0.f;
        float bbx2 = valid ? bx2[sel] : 0.f;
        float bby2 = valid ? by2[sel] : 0.f;
        float bcfs = valid ? bcf[sel] : 0.f;
        best_iou   = valid ? best_iou : 0.f;

        float dx = bbx1 - tx1, dy = bby1 - ty1;
        float lxy = dx * dx + dy * dy;
        float swx = bbx2 > 0.f ? sqrtf(bbx2) : 0.f;
        float swy = bby2 > 0.f ? sqrtf(bby2) : 0.f;
        float twx = tx2  > 0.f ? sqrtf(tx2)  : 0.f;
        float twy = ty2  > 0.f ? sqrtf(ty2)  : 0.f;
        float dwx = swx - twx, dwy = swy - twy;
        reg = fm * (lxy + dwx * dwx + dwy * dwy);

        float c0 = q[4], c1 = q[9];
        nbj = (1.f - fm) * (c0 * c0 + c1 * c1);

        float dcf = bcfs - best_iou;
        cobj = fm * dcf * dcf;
    }

    // ---- cls loss: flat element split across lanes, mask via __shfl ----
    #pragma unroll
    for (int i = 0; i < 5; ++i) {
        int e    = lane + 64 * i;                // [0, 320) float4-groups
        int cell = e / 5;
        int c0i  = (e - cell * 5) * 4;
        const float* pc = swave + cell * 30 + 10 + c0i;
        float mk = __shfl(fm, cell, 64);
        float4 tv = tcv[i];
        float d0 = pc[0] - tv.x, d1 = pc[1] - tv.y;
        float d2 = pc[2] - tv.z, d3 = pc[3] - tv.w;
        clsv += mk * (d0 * d0 + d1 * d1 + d2 * d2 + d3 * d3);
    }

    // ---- reduction: wave64 shuffle, then cross-wave via LDS ----
    #pragma unroll
    for (int off = 32; off > 0; off >>= 1) {
        reg  += __shfl_down(reg,  off);
        cobj += __shfl_down(cobj, off);
        nbj  += __shfl_down(nbj,  off);
        clsv += __shfl_down(clsv, off);
    }
    if (lane == 0) {
        sred[wid][0] = reg; sred[wid][1] = cobj;
        sred[wid][2] = nbj; sred[wid][3] = clsv;
    }
    __syncthreads();
    if (tid == 0) {
        float4 s;
        s.x = sred[0][0] + sred[1][0] + sred[2][0] + sred[3][0];
        s.y = sred[0][1] + sred[1][1] + sred[2][1] + sred[3][1];
        s.z = sred[0][2] + sred[1][2] + sred[2][2] + sred[3][2];
        s.w = sred[0][3] + sred[1][3] + sred[2][3] + sred[3][3];
        partials[blockIdx.x] = s;
    }
}

__global__ __launch_bounds__(256) void yolo_finalize(
    const float4* __restrict__ partials, float* __restrict__ out)
{
    float4 s = {0.f, 0.f, 0.f, 0.f};
    for (int b = threadIdx.x; b < NBLK; b += 256) {
        float4 v = partials[b];
        s.x += v.x; s.y += v.y; s.z += v.z; s.w += v.w;
    }
    #pragma unroll
    for (int off = 32; off > 0; off >>= 1) {
        s.x += __shfl_down(s.x, off);
        s.y += __shfl_down(s.y, off);
        s.z += __shfl_down(s.z, off);
        s.w += __shfl_down(s.w, off);
    }
    __shared__ float4 sw[4];
    int wave = threadIdx.x >> 6, lane = threadIdx.x & 63;
    if (lane == 0) sw[wave] = s;
    __syncthreads();
    if (threadIdx.x == 0) {
        float r = 0.f, c = 0.f, n = 0.f, cl = 0.f;
        #pragma unroll
        for (int w = 0; w < 4; ++w) {
            r += sw[w].x; c += sw[w].y; n += sw[w].z; cl += sw[w].w;
        }
        const float invN = 1.0f / NBATCH;
        float reg_l  = L_COORD * r * invN;
        float cobj_l = c * invN;
        float nbj_l  = L_NOOBJ * n * invN;
        float cls_l  = 2.0f * cl * invN;
        out[0] = cls_l + nbj_l + reg_l + cobj_l;
        out[1] = reg_l;
        out[2] = cobj_l;
        out[3] = nbj_l;
        out[4] = cls_l;
    }
}

extern "C" void kernel_launch(void* const* d_in, const int* in_sizes, int n_in,
                              void* d_out, int out_size, void* d_ws, size_t ws_size,
                              hipStream_t stream) {
    const float* pred   = (const float*)d_in[0];
    const float* tboxes = (const float*)d_in[1];
    const float* tcls   = (const float*)d_in[2];
    const int*   objmap = (const int*)d_in[3];
    float4* partials = (float4*)d_ws;
    float*  out      = (float*)d_out;

    yolo_main<<<NBLK, 256, 0, stream>>>(pred, tboxes, tcls, objmap, partials);
    yolo_finalize<<<1, 256, 0, stream>>>(partials, out);
}